// Round 18
// baseline (178.889 us; speedup 1.0000x reference)
//
#include <hip/hip_runtime.h>
#include <hip/hip_bf16.h>
#include <cstdint>

typedef __attribute__((ext_vector_type(4))) float f32x4;
typedef __attribute__((ext_vector_type(8))) short s16x8;

#define NB   32
#define NL   2048
#define NH   512
#define NM   (NB * NL)          // 65536 rows
#define SCALE 0.04419417382415922f  // 1/sqrt(512)

__device__ __forceinline__ ushort f2bf(float f) {
    __hip_bfloat16 b = __float2bfloat16(f);   // pairs fuse into v_cvt_pk_bf16_f32
    return *reinterpret_cast<ushort*>(&b);
}
__device__ __forceinline__ unsigned long long pack4(float4 f) {
    union { ushort u[4]; unsigned long long v; } p;
    p.u[0] = f2bf(f.x); p.u[1] = f2bf(f.y); p.u[2] = f2bf(f.z); p.u[3] = f2bf(f.w);
    return p.v;
}

// async global->LDS, 16B/lane: dest = wave-uniform base + lane*16; global addr per-lane
#define GL16(g, l)                                                         \
    __builtin_amdgcn_global_load_lds(                                      \
        (const __attribute__((address_space(1))) unsigned int*)(g),        \
        (__attribute__((address_space(3))) unsigned int*)(l), 16, 0, 0)

// ============================================================================
// k_pre: convW (blocks 0..63) + eq (blocks 64..95). Tiny (~5 us).
// ============================================================================
__global__ __launch_bounds__(256) void k_pre(const float* __restrict__ W,
                                             ushort* __restrict__ Wb,
                                             const float* __restrict__ query,
                                             const float* __restrict__ Wq,
                                             float* __restrict__ eq) {
    int bid = blockIdx.x;
    int t = threadIdx.x;
    if (bid < 64) {
        const float4* F = (const float4*)W;
        unsigned long long* U = (unsigned long long*)Wb;
        int base = bid * 1024 + t;
        float4 f[4];
#pragma unroll
        for (int k = 0; k < 4; ++k) f[k] = F[base + k * 256];
#pragma unroll
        for (int k = 0; k < 4; ++k) U[base + k * 256] = pack4(f[k]);
    } else {
        __shared__ float q[NH];
        int b = bid - 64;
        q[t] = query[b * NH + t];
        q[t + 256] = query[b * NH + t + 256];
        __syncthreads();
#pragma unroll
        for (int half = 0; half < 2; ++half) {
            int o = t + half * 256;
            const float4* w = (const float4*)(Wq + (size_t)o * NH);
            float acc = 0.f;
#pragma unroll 4
            for (int i = 0; i < NH / 4; ++i) {
                float4 x = w[i];
                acc += q[4 * i] * x.x + q[4 * i + 1] * x.y + q[4 * i + 2] * x.z + q[4 * i + 3] * x.w;
            }
            eq[b * NH + o] = acc;
        }
    }
}

// ============================================================================
// k_gemm8 v2: R16's proven T3/T4 skeleton + FUSED A conversion (conv deleted).
// 512 blocks x 512 thr (8 waves). BM=256, BN=256 (2 n-tiles), BK=64, 8 K-tiles.
// A: f32 reg-load (coalesced 4 rows x 256B per instr) -> cvt once -> swizzled
//    ds_write (chunk ^= row&7, same involution as frag read).
// B: gl16 with pre-swizzled global source (unchanged).
// Stage/wave = [A-loads x8, B-gl16 x4]. Entry: lgkm0+vmcnt(12) (drains B(kt));
// tail: vmcnt(4) (drains A(kt+1)) -> WRITE_A(kt+1) -> stage(kt+2).
// ============================================================================
__global__ __launch_bounds__(512, 1) void k_gemm8(const float* __restrict__ ref,
                                                  const ushort* __restrict__ Wb,
                                                  const float* __restrict__ eq,
                                                  const float* __restrict__ v,
                                                  float* __restrict__ part) {
    __shared__ ushort smem[65536];               // 128 KB
    ushort* As0 = smem;                          // [256][64] bf16
    ushort* Bs0 = smem + 16384;
    ushort* As1 = smem + 32768;
    ushort* Bs1 = smem + 49152;

    int tid = threadIdx.x;
    int lane = tid & 63, wid = tid >> 6;         // 8 waves
    int wr = wid >> 2, wc = wid & 3;

    int phys = blockIdx.x;                       // 512 blocks
    int xcd = phys & 7, slot = phys >> 3;        // sibling n-tiles same XCD
    int mt = xcd * 32 + (slot >> 1);             // 256 m-tiles
    int nt = slot & 1;                           // 2 n-tiles
    int m0g = mt << 8, n0 = nt << 8;             // 256 rows / 256 cols
    int b = mt >> 3;                             // batch (8 m-tiles per batch)

    f32x4 acc[8][4];
#pragma unroll
    for (int i = 0; i < 8; ++i)
#pragma unroll
        for (int j = 0; j < 4; ++j) acc[i][j] = (f32x4)(0.f);

    int lr = lane & 15, kq = lane >> 4;
    int l7 = lr & 7;
    int sA0 = ((kq) ^ l7) << 3;                  // k-chunk slot (ushorts)
    int sA1 = ((4 + kq) ^ l7) << 3;
    int abase0 = (wr * 128 + lr) * 64;           // + fr*1024
    int bbase0 = (wc * 64 + lr) * 64;            // + fc*1024

    // A reg staging: lane -> row wid*32 + (l>>4) (+j*4), f4 slot (l&15)
    const float* aglob = ref + (size_t)(m0g + wid * 32 + (lane >> 4)) * NH + (lane & 15) * 4;
    float4 qa[8];

#define STAGE_A(kt)                                                            \
    {   _Pragma("unroll")                                                      \
        for (int j = 0; j < 8; ++j)                                            \
            qa[j] = *(const float4*)(aglob + (size_t)(j * 4) * NH + (kt) * 64); }

#define WRITE_A(Asb)                                                           \
    {   int s_ = lane & 15;                                                    \
        _Pragma("unroll")                                                      \
        for (int j = 0; j < 8; ++j) {                                          \
            int rowj = wid * 32 + (lane >> 4) + j * 4;                         \
            int idx = rowj * 64 + ((((s_ >> 1) ^ (rowj & 7))) << 3) + ((s_ & 1) << 2); \
            *(unsigned long long*)&(Asb)[idx] = pack4(qa[j]);                  \
        } }

#define STAGE_B(Bsb, kt)                                                       \
    {   _Pragma("unroll")                                                      \
        for (int ho = 0; ho < 4; ++ho) {                                       \
            int br = wid * 32 + ho * 8;                                        \
            int rl = br + (lane >> 3);                                         \
            int gc = (lane & 7) ^ (rl & 7);                                    \
            GL16(Wb + (size_t)(n0 + rl) * NH + (kt) * 64 + gc * 8, (Bsb) + br * 64); \
        } }

#define TILE_BODY(Asb, Bsb)                                                    \
    {   s16x8 bq[4][2];                                                        \
        _Pragma("unroll")                                                      \
        for (int fc = 0; fc < 4; ++fc) {                                       \
            bq[fc][0] = *(const s16x8*)&(Bsb)[bbase0 + fc * 1024 + sA0];       \
            bq[fc][1] = *(const s16x8*)&(Bsb)[bbase0 + fc * 1024 + sA1];       \
        }                                                                      \
        __builtin_amdgcn_s_setprio(1);                                         \
        _Pragma("unroll")                                                      \
        for (int fr = 0; fr < 8; ++fr) {                                       \
            s16x8 a0 = *(const s16x8*)&(Asb)[abase0 + fr * 1024 + sA0];        \
            s16x8 a1 = *(const s16x8*)&(Asb)[abase0 + fr * 1024 + sA1];        \
            _Pragma("unroll")                                                  \
            for (int fc = 0; fc < 4; ++fc) {                                   \
                acc[fr][fc] = __builtin_amdgcn_mfma_f32_16x16x32_bf16(         \
                    a0, bq[fc][0], acc[fr][fc], 0, 0, 0);                      \
                acc[fr][fc] = __builtin_amdgcn_mfma_f32_16x16x32_bf16(         \
                    a1, bq[fc][1], acc[fr][fc], 0, 0, 0);                      \
            }                                                                  \
        }                                                                      \
        __builtin_amdgcn_s_setprio(0);                                         \
    }

    // phase entry: drain own ds_writes (visibility via barrier) + B(kt)
#define ENTRY(N)                                                               \
    asm volatile("s_waitcnt lgkmcnt(0)" ::: "memory");                         \
    asm volatile("s_waitcnt vmcnt(" #N ")" ::: "memory");                      \
    __builtin_amdgcn_s_barrier();

#define EXIT()                                                                 \
    asm volatile("s_waitcnt lgkmcnt(0)" ::: "memory");                         \
    __builtin_amdgcn_s_barrier();

    // ---- prologue: A(0),B(0); A(0)->LDS; A(1),B(1) ----
    STAGE_A(0) STAGE_B(Bs0, 0)
    asm volatile("s_waitcnt vmcnt(4)" ::: "memory");   // A(0) landed (B(0) flying)
    WRITE_A(As0)
    STAGE_A(1) STAGE_B(Bs1, 1)

    // ---- 8 K-tiles ----
    ENTRY(12) TILE_BODY(As0, Bs0) EXIT()               // kt=0
    asm volatile("s_waitcnt vmcnt(4)" ::: "memory"); WRITE_A(As1) STAGE_A(2) STAGE_B(Bs0, 2)
    ENTRY(12) TILE_BODY(As1, Bs1) EXIT()               // kt=1
    asm volatile("s_waitcnt vmcnt(4)" ::: "memory"); WRITE_A(As0) STAGE_A(3) STAGE_B(Bs1, 3)
    ENTRY(12) TILE_BODY(As0, Bs0) EXIT()               // kt=2
    asm volatile("s_waitcnt vmcnt(4)" ::: "memory"); WRITE_A(As1) STAGE_A(4) STAGE_B(Bs0, 4)
    ENTRY(12) TILE_BODY(As1, Bs1) EXIT()               // kt=3
    asm volatile("s_waitcnt vmcnt(4)" ::: "memory"); WRITE_A(As0) STAGE_A(5) STAGE_B(Bs1, 5)
    ENTRY(12) TILE_BODY(As0, Bs0) EXIT()               // kt=4
    asm volatile("s_waitcnt vmcnt(4)" ::: "memory"); WRITE_A(As1) STAGE_A(6) STAGE_B(Bs0, 6)
    ENTRY(12) TILE_BODY(As1, Bs1) EXIT()               // kt=5
    asm volatile("s_waitcnt vmcnt(4)" ::: "memory"); WRITE_A(As0) STAGE_A(7) STAGE_B(Bs1, 7)
    ENTRY(12) TILE_BODY(As0, Bs0) EXIT()               // kt=6
    asm volatile("s_waitcnt vmcnt(4)" ::: "memory"); WRITE_A(As1)
    ENTRY(0)  TILE_BODY(As1, Bs1)                      // kt=7

#undef STAGE_A
#undef WRITE_A
#undef STAGE_B
#undef TILE_BODY
#undef ENTRY
#undef EXIT

    __syncthreads();                             // before sc_red overlay

    // ---- epilogue: partial v-dot over this block's 256 cols ----
    float* sc_red = (float*)smem;                // [8][128]
    const float* eqb = eq + b * NH;
    float vv[4], ee[4];
#pragma unroll
    for (int fc = 0; fc < 4; ++fc) {
        int c = n0 + wc * 64 + fc * 16 + lr;
        vv[fc] = v[c];
        ee[fc] = eqb[c];
    }
#pragma unroll
    for (int fr = 0; fr < 8; ++fr) {
#pragma unroll
        for (int reg = 0; reg < 4; ++reg) {
            float s = 0.f;
#pragma unroll
            for (int fc = 0; fc < 4; ++fc) {
                float x = acc[fr][fc][reg] + ee[fc];
                float t = 1.f - 2.f / (__expf(2.f * x) + 1.f);  // tanh
                s += vv[fc] * t;
            }
            s += __shfl_xor(s, 1);
            s += __shfl_xor(s, 2);
            s += __shfl_xor(s, 4);
            s += __shfl_xor(s, 8);
            if (lr == 0) sc_red[wid * 128 + fr * 16 + kq * 4 + reg] = s;
        }
    }
    __syncthreads();
    if (tid < 256) {
        int row = tid;
        int g0 = (row >> 7) * 4;
        int rl = row & 127;
        float s = sc_red[(g0 + 0) * 128 + rl] + sc_red[(g0 + 1) * 128 + rl]
                + sc_red[(g0 + 2) * 128 + rl] + sc_red[(g0 + 3) * 128 + rl];
        part[(size_t)nt * NM + m0g + row] = s;
    }
}

// ============================================================================
// k_smglp: combine nt-partials + mask -> scores; softmax; glimpse slice (f32).
// grid (16 sp, 32 b). sp==0 writes out_sc.
// ============================================================================
__global__ __launch_bounds__(256) void k_smglp(const float* __restrict__ part,
                                               const int* __restrict__ mask,
                                               const float* __restrict__ ref,
                                               float* __restrict__ out_sc,
                                               float* __restrict__ glp) {
    int sp = blockIdx.x, b = blockIdx.y;
    int tid = threadIdx.x;
    int lane = tid & 63, wid = tid >> 6;
    __shared__ float red[4];
    __shared__ float asl[128];    // unnormalized exp for rows sp*128..+128
    float sc[8];
    float mx = -3.4e38f;
#pragma unroll
    for (int i = 0; i < 8; ++i) {
        int m = b * NL + i * 256 + tid;
        float s = (part[m] + part[NM + m]) * SCALE;
        if (mask[m] != 0) s = -1e9f;
        if (sp == 0) out_sc[m] = s;
        sc[i] = s;
        mx = fmaxf(mx, s);
    }
#pragma unroll
    for (int o = 32; o >= 1; o >>= 1) mx = fmaxf(mx, __shfl_xor(mx, o));
    if (lane == 0) red[wid] = mx;
    __syncthreads();
    mx = fmaxf(fmaxf(red[0], red[1]), fmaxf(red[2], red[3]));
    __syncthreads();
    float ls = 0.f;
#pragma unroll
    for (int i = 0; i < 8; ++i) {
        float e = __expf(sc[i] - mx);
        ls += e;
        if (i == (sp >> 1) && (tid >> 7) == (sp & 1)) asl[tid & 127] = e;
    }
#pragma unroll
    for (int o = 32; o >= 1; o >>= 1) ls += __shfl_xor(ls, o);
    if (lane == 0) red[wid] = ls;
    __syncthreads();
    float inv = 1.f / (red[0] + red[1] + red[2] + red[3]);

    const float* rb = ref + ((size_t)b * NL + sp * 128) * NH;
    float2 acc = make_float2(0.f, 0.f);
#pragma unroll 4
    for (int l = 0; l < 128; ++l) {
        float a = asl[l];
        float2 r = ((const float2*)(rb + (size_t)l * NH))[tid];
        acc.x += a * r.x;
        acc.y += a * r.y;
    }
    acc.x *= inv;
    acc.y *= inv;
    ((float2*)(glp + (size_t)(sp * NB + b) * NH))[tid] = acc;
}

// ---- reduce glimpse partials (16 splits) ----
__global__ __launch_bounds__(256) void k_gred(const float* __restrict__ glp,
                                              float* __restrict__ out_gl) {
    int idx = blockIdx.x * 256 + threadIdx.x;   // 16384 = B*H
    float s = 0.f;
#pragma unroll
    for (int sp = 0; sp < 16; ++sp) s += glp[sp * (NB * NH) + idx];
    out_gl[idx] = s;
}

extern "C" void kernel_launch(void* const* d_in, const int* in_sizes, int n_in,
                              void* d_out, int out_size, void* d_ws, size_t ws_size,
                              hipStream_t stream) {
    const float* query = (const float*)d_in[0];
    const float* ref   = (const float*)d_in[1];
    const int*   mask  = (const int*)d_in[2];
    const float* W_ref = (const float*)d_in[3];
    const float* W_q   = (const float*)d_in[4];
    const float* v     = (const float*)d_in[5];

    float* out_gl = (float*)d_out;              // 32*512
    float* out_sc = out_gl + NB * NH;           // 32*2048 (final scores)

    char* w = (char*)d_ws;
    ushort* wW   = (ushort*)w;                  // 524,288 B @ 0
    float*  eq   = (float*)(w + 524288);        // 65,536 B
    float*  part = (float*)(w + 589824);        // 524,288 B (2 slices)
    float*  glp  = (float*)(w + 1114112);       // 1,048,576 B (16 splits)

    k_pre<<<96, 256, 0, stream>>>(W_ref, wW, query, W_q, eq);
    k_gemm8<<<512, 512, 0, stream>>>(ref, wW, eq, v, part);
    k_smglp<<<dim3(16, NB), 256, 0, stream>>>(part, mask, ref, out_sc, glp);
    k_gred<<<64, 256, 0, stream>>>(glp, out_gl);
}

// Round 19
// 129.585 us; speedup vs baseline: 1.3805x; 1.3805x over previous
//
#include <hip/hip_runtime.h>
#include <hip/hip_bf16.h>
#include <cstdint>

typedef __attribute__((ext_vector_type(4))) float f32x4;
typedef __attribute__((ext_vector_type(8))) short s16x8;

#define NB   32
#define NL   2048
#define NH   512
#define NM   (NB * NL)          // 65536 rows
#define SCALE 0.04419417382415922f  // 1/sqrt(512)

__device__ __forceinline__ ushort f2bf(float f) {
    __hip_bfloat16 b = __float2bfloat16(f);   // pairs fuse into v_cvt_pk_bf16_f32
    return *reinterpret_cast<ushort*>(&b);
}
__device__ __forceinline__ unsigned long long pack4(float4 f) {
    union { ushort u[4]; unsigned long long v; } p;
    p.u[0] = f2bf(f.x); p.u[1] = f2bf(f.y); p.u[2] = f2bf(f.z); p.u[3] = f2bf(f.w);
    return p.v;
}

// async global->LDS, 16B/lane: dest = wave-uniform base + lane*16; global addr per-lane
#define GL16(g, l)                                                         \
    __builtin_amdgcn_global_load_lds(                                      \
        (const __attribute__((address_space(1))) unsigned int*)(g),        \
        (__attribute__((address_space(3))) unsigned int*)(l), 16, 0, 0)

// ============================================================================
// k_pre: convW (blocks 0..63) + eq (blocks 64..95). Tiny (~5 us).
// ============================================================================
__global__ __launch_bounds__(256) void k_pre(const float* __restrict__ W,
                                             ushort* __restrict__ Wb,
                                             const float* __restrict__ query,
                                             const float* __restrict__ Wq,
                                             float* __restrict__ eq) {
    int bid = blockIdx.x;
    int t = threadIdx.x;
    if (bid < 64) {
        const float4* F = (const float4*)W;
        unsigned long long* U = (unsigned long long*)Wb;
        int base = bid * 1024 + t;
        float4 f[4];
#pragma unroll
        for (int k = 0; k < 4; ++k) f[k] = F[base + k * 256];
#pragma unroll
        for (int k = 0; k < 4; ++k) U[base + k * 256] = pack4(f[k]);
    } else {
        __shared__ float q[NH];
        int b = bid - 64;
        q[t] = query[b * NH + t];
        q[t + 256] = query[b * NH + t + 256];
        __syncthreads();
#pragma unroll
        for (int half = 0; half < 2; ++half) {
            int o = t + half * 256;
            const float4* w = (const float4*)(Wq + (size_t)o * NH);
            float acc = 0.f;
#pragma unroll 4
            for (int i = 0; i < NH / 4; ++i) {
                float4 x = w[i];
                acc += q[4 * i] * x.x + q[4 * i + 1] * x.y + q[4 * i + 2] * x.z + q[4 * i + 3] * x.w;
            }
            eq[b * NH + o] = acc;
        }
    }
}

// ============================================================================
// k_gemm8 v3: fused-A-conversion 8-tile GEMM, REGISTER-FIT (R18 spilled at
// BM=256: qa[8]+acc128 > budget -> 143 MB scratch; this halves both).
// 1024 blocks x 512 thr (8 waves). BM=128, BN=256 (2 n-tiles), BK=64, 8 K-tiles.
// Wave tile 64x64 (acc 4x4 = 64 AGPR). A: qa[4] f32 reg-load -> cvt once ->
// swizzled ds_write. B: gl16, pre-swizzled source. LDS 96 KB -> 1 block/CU.
// Stage/wave = 4 A-loads + 4 B-gl16. ENTRY: lgkm0 + vmcnt(8) (drains B(kt));
// tail: vmcnt(4) (drains A(kt+1)) -> WRITE_A -> stage(kt+2).
// ============================================================================
__global__ __launch_bounds__(512, 1) void k_gemm8(const float* __restrict__ ref,
                                                  const ushort* __restrict__ Wb,
                                                  const float* __restrict__ eq,
                                                  const float* __restrict__ v,
                                                  float* __restrict__ part) {
    __shared__ ushort smem[49152];               // 96 KB
    ushort* As0 = smem;                          // [128][64] bf16, 16 KB
    ushort* Bs0 = smem + 8192;                   // [256][64] bf16, 32 KB
    ushort* As1 = smem + 24576;                  // 16 KB
    ushort* Bs1 = smem + 32768;                  // 32 KB

    int tid = threadIdx.x;
    int lane = tid & 63, wid = tid >> 6;         // 8 waves
    int wr = wid >> 2, wc = wid & 3;             // 2 x 4 wave grid

    int phys = blockIdx.x;                       // 1024 blocks
    int xcd = phys & 7, slot = phys >> 3;        // sibling n-tiles same XCD
    int mt = xcd * 64 + (slot >> 1);             // 512 m-tiles (128 rows each)
    int nt = slot & 1;                           // 2 n-tiles
    int m0g = mt << 7, n0 = nt << 8;             // 128 rows / 256 cols
    int b = mt >> 4;                             // batch (16 m-tiles per batch)

    f32x4 acc[4][4];
#pragma unroll
    for (int i = 0; i < 4; ++i)
#pragma unroll
        for (int j = 0; j < 4; ++j) acc[i][j] = (f32x4)(0.f);

    int lr = lane & 15, kq = lane >> 4;
    int l7 = lr & 7;
    int sA0 = ((kq) ^ l7) << 3;                  // k-chunk slot (ushorts)
    int sA1 = ((4 + kq) ^ l7) << 3;
    int abase0 = (wr * 64 + lr) * 64;            // + fr*1024  ([128][64])
    int bbase0 = (wc * 64 + lr) * 64;            // + fc*1024  ([256][64])

    // A reg staging: wave wid stages rows wid*16..+16; lane -> row + (l>>4) (+j*4)
    const float* aglob = ref + (size_t)(m0g + wid * 16 + (lane >> 4)) * NH + (lane & 15) * 4;
    float4 qa[4];

#define STAGE_A(kt)                                                            \
    {   _Pragma("unroll")                                                      \
        for (int j = 0; j < 4; ++j)                                            \
            qa[j] = *(const float4*)(aglob + (size_t)(j * 4) * NH + (kt) * 64); }

#define WRITE_A(Asb)                                                           \
    {   int s_ = lane & 15;                                                    \
        _Pragma("unroll")                                                      \
        for (int j = 0; j < 4; ++j) {                                          \
            int rowj = wid * 16 + (lane >> 4) + j * 4;                         \
            int idx = rowj * 64 + ((((s_ >> 1) ^ (rowj & 7))) << 3) + ((s_ & 1) << 2); \
            *(unsigned long long*)&(Asb)[idx] = pack4(qa[j]);                  \
        } }

#define STAGE_B(Bsb, kt)                                                       \
    {   _Pragma("unroll")                                                      \
        for (int ho = 0; ho < 4; ++ho) {                                       \
            int br = wid * 32 + ho * 8;                                        \
            int rl = br + (lane >> 3);                                         \
            int gc = (lane & 7) ^ (rl & 7);                                    \
            GL16(Wb + (size_t)(n0 + rl) * NH + (kt) * 64 + gc * 8, (Bsb) + br * 64); \
        } }

#define TILE_BODY(Asb, Bsb)                                                    \
    {   s16x8 bq[4][2];                                                        \
        _Pragma("unroll")                                                      \
        for (int fc = 0; fc < 4; ++fc) {                                       \
            bq[fc][0] = *(const s16x8*)&(Bsb)[bbase0 + fc * 1024 + sA0];       \
            bq[fc][1] = *(const s16x8*)&(Bsb)[bbase0 + fc * 1024 + sA1];       \
        }                                                                      \
        __builtin_amdgcn_s_setprio(1);                                         \
        _Pragma("unroll")                                                      \
        for (int fr = 0; fr < 4; ++fr) {                                       \
            s16x8 a0 = *(const s16x8*)&(Asb)[abase0 + fr * 1024 + sA0];        \
            s16x8 a1 = *(const s16x8*)&(Asb)[abase0 + fr * 1024 + sA1];        \
            _Pragma("unroll")                                                  \
            for (int fc = 0; fc < 4; ++fc) {                                   \
                acc[fr][fc] = __builtin_amdgcn_mfma_f32_16x16x32_bf16(         \
                    a0, bq[fc][0], acc[fr][fc], 0, 0, 0);                      \
                acc[fr][fc] = __builtin_amdgcn_mfma_f32_16x16x32_bf16(         \
                    a1, bq[fc][1], acc[fr][fc], 0, 0, 0);                      \
            }                                                                  \
        }                                                                      \
        __builtin_amdgcn_s_setprio(0);                                         \
    }

#define ENTRY(N)                                                               \
    asm volatile("s_waitcnt lgkmcnt(0)" ::: "memory");                         \
    asm volatile("s_waitcnt vmcnt(" #N ")" ::: "memory");                      \
    __builtin_amdgcn_s_barrier();

#define EXIT()                                                                 \
    asm volatile("s_waitcnt lgkmcnt(0)" ::: "memory");                         \
    __builtin_amdgcn_s_barrier();

    // ---- prologue: A(0),B(0); A(0)->LDS; A(1),B(1) ----
    STAGE_A(0) STAGE_B(Bs0, 0)
    asm volatile("s_waitcnt vmcnt(4)" ::: "memory");   // A(0) landed (B(0) flying)
    WRITE_A(As0)
    STAGE_A(1) STAGE_B(Bs1, 1)
    // queue: B(0)4, A(1)4, B(1)4 = 12

    // ---- 8 K-tiles ----
    ENTRY(8)  TILE_BODY(As0, Bs0) EXIT()               // kt=0 (drains B(0))
    asm volatile("s_waitcnt vmcnt(4)" ::: "memory"); WRITE_A(As1) STAGE_A(2) STAGE_B(Bs0, 2)
    ENTRY(8)  TILE_BODY(As1, Bs1) EXIT()               // kt=1
    asm volatile("s_waitcnt vmcnt(4)" ::: "memory"); WRITE_A(As0) STAGE_A(3) STAGE_B(Bs1, 3)
    ENTRY(8)  TILE_BODY(As0, Bs0) EXIT()               // kt=2
    asm volatile("s_waitcnt vmcnt(4)" ::: "memory"); WRITE_A(As1) STAGE_A(4) STAGE_B(Bs0, 4)
    ENTRY(8)  TILE_BODY(As1, Bs1) EXIT()               // kt=3
    asm volatile("s_waitcnt vmcnt(4)" ::: "memory"); WRITE_A(As0) STAGE_A(5) STAGE_B(Bs1, 5)
    ENTRY(8)  TILE_BODY(As0, Bs0) EXIT()               // kt=4
    asm volatile("s_waitcnt vmcnt(4)" ::: "memory"); WRITE_A(As1) STAGE_A(6) STAGE_B(Bs0, 6)
    ENTRY(8)  TILE_BODY(As1, Bs1) EXIT()               // kt=5
    asm volatile("s_waitcnt vmcnt(4)" ::: "memory"); WRITE_A(As0) STAGE_A(7) STAGE_B(Bs1, 7)
    ENTRY(8)  TILE_BODY(As0, Bs0) EXIT()               // kt=6
    asm volatile("s_waitcnt vmcnt(4)" ::: "memory"); WRITE_A(As1)
    ENTRY(0)  TILE_BODY(As1, Bs1)                      // kt=7

#undef STAGE_A
#undef WRITE_A
#undef STAGE_B
#undef TILE_BODY
#undef ENTRY
#undef EXIT

    __syncthreads();                             // before sc_red overlay

    // ---- epilogue: partial v-dot over this block's 256 cols ----
    float* sc_red = (float*)smem;                // [8][64]
    const float* eqb = eq + b * NH;
    float vv[4], ee[4];
#pragma unroll
    for (int fc = 0; fc < 4; ++fc) {
        int c = n0 + wc * 64 + fc * 16 + lr;
        vv[fc] = v[c];
        ee[fc] = eqb[c];
    }
#pragma unroll
    for (int fr = 0; fr < 4; ++fr) {
#pragma unroll
        for (int reg = 0; reg < 4; ++reg) {
            float s = 0.f;
#pragma unroll
            for (int fc = 0; fc < 4; ++fc) {
                float x = acc[fr][fc][reg] + ee[fc];
                float t = 1.f - 2.f / (__expf(2.f * x) + 1.f);  // tanh
                s += vv[fc] * t;
            }
            s += __shfl_xor(s, 1);
            s += __shfl_xor(s, 2);
            s += __shfl_xor(s, 4);
            s += __shfl_xor(s, 8);
            if (lr == 0) sc_red[wid * 64 + fr * 16 + kq * 4 + reg] = s;
        }
    }
    __syncthreads();
    if (tid < 128) {
        int row = tid;
        int g0 = (row >> 6) * 4;                 // waves 0-3 -> rows 0-63; 4-7 -> 64-127
        int rl = row & 63;
        float s = sc_red[(g0 + 0) * 64 + rl] + sc_red[(g0 + 1) * 64 + rl]
                + sc_red[(g0 + 2) * 64 + rl] + sc_red[(g0 + 3) * 64 + rl];
        part[(size_t)nt * NM + m0g + row] = s;
    }
}

// ============================================================================
// k_smglp: combine nt-partials + mask -> scores; softmax; glimpse slice (f32).
// grid (16 sp, 32 b). sp==0 writes out_sc.
// ============================================================================
__global__ __launch_bounds__(256) void k_smglp(const float* __restrict__ part,
                                               const int* __restrict__ mask,
                                               const float* __restrict__ ref,
                                               float* __restrict__ out_sc,
                                               float* __restrict__ glp) {
    int sp = blockIdx.x, b = blockIdx.y;
    int tid = threadIdx.x;
    int lane = tid & 63, wid = tid >> 6;
    __shared__ float red[4];
    __shared__ float asl[128];    // unnormalized exp for rows sp*128..+128
    float sc[8];
    float mx = -3.4e38f;
#pragma unroll
    for (int i = 0; i < 8; ++i) {
        int m = b * NL + i * 256 + tid;
        float s = (part[m] + part[NM + m]) * SCALE;
        if (mask[m] != 0) s = -1e9f;
        if (sp == 0) out_sc[m] = s;
        sc[i] = s;
        mx = fmaxf(mx, s);
    }
#pragma unroll
    for (int o = 32; o >= 1; o >>= 1) mx = fmaxf(mx, __shfl_xor(mx, o));
    if (lane == 0) red[wid] = mx;
    __syncthreads();
    mx = fmaxf(fmaxf(red[0], red[1]), fmaxf(red[2], red[3]));
    __syncthreads();
    float ls = 0.f;
#pragma unroll
    for (int i = 0; i < 8; ++i) {
        float e = __expf(sc[i] - mx);
        ls += e;
        if (i == (sp >> 1) && (tid >> 7) == (sp & 1)) asl[tid & 127] = e;
    }
#pragma unroll
    for (int o = 32; o >= 1; o >>= 1) ls += __shfl_xor(ls, o);
    if (lane == 0) red[wid] = ls;
    __syncthreads();
    float inv = 1.f / (red[0] + red[1] + red[2] + red[3]);

    const float* rb = ref + ((size_t)b * NL + sp * 128) * NH;
    float2 acc = make_float2(0.f, 0.f);
#pragma unroll 4
    for (int l = 0; l < 128; ++l) {
        float a = asl[l];
        float2 r = ((const float2*)(rb + (size_t)l * NH))[tid];
        acc.x += a * r.x;
        acc.y += a * r.y;
    }
    acc.x *= inv;
    acc.y *= inv;
    ((float2*)(glp + (size_t)(sp * NB + b) * NH))[tid] = acc;
}

// ---- reduce glimpse partials (16 splits) ----
__global__ __launch_bounds__(256) void k_gred(const float* __restrict__ glp,
                                              float* __restrict__ out_gl) {
    int idx = blockIdx.x * 256 + threadIdx.x;   // 16384 = B*H
    float s = 0.f;
#pragma unroll
    for (int sp = 0; sp < 16; ++sp) s += glp[sp * (NB * NH) + idx];
    out_gl[idx] = s;
}

extern "C" void kernel_launch(void* const* d_in, const int* in_sizes, int n_in,
                              void* d_out, int out_size, void* d_ws, size_t ws_size,
                              hipStream_t stream) {
    const float* query = (const float*)d_in[0];
    const float* ref   = (const float*)d_in[1];
    const int*   mask  = (const int*)d_in[2];
    const float* W_ref = (const float*)d_in[3];
    const float* W_q   = (const float*)d_in[4];
    const float* v     = (const float*)d_in[5];

    float* out_gl = (float*)d_out;              // 32*512
    float* out_sc = out_gl + NB * NH;           // 32*2048 (final scores)

    char* w = (char*)d_ws;
    ushort* wW   = (ushort*)w;                  // 524,288 B @ 0
    float*  eq   = (float*)(w + 524288);        // 65,536 B
    float*  part = (float*)(w + 589824);        // 524,288 B (2 slices)
    float*  glp  = (float*)(w + 1114112);       // 1,048,576 B (16 splits)

    k_pre<<<96, 256, 0, stream>>>(W_ref, wW, query, W_q, eq);
    k_gemm8<<<1024, 512, 0, stream>>>(ref, wW, eq, v, part);
    k_smglp<<<dim3(16, NB), 256, 0, stream>>>(part, mask, ref, out_sc, glp);
    k_gred<<<64, 256, 0, stream>>>(glp, out_gl);
}